// Round 5
// baseline (125.547 us; speedup 1.0000x reference)
//
#include <hip/hip_runtime.h>
#include <stdint.h>

#define NROWS 8192
#define KDIM  512
#define BM    128
#define BK    32
#define NT    (NROWS / BM)                  // 64 tiles per dim
#define NKT   (KDIM / BK)                   // 16 k-tiles

typedef __attribute__((ext_vector_type(8))) short bf16x8;
typedef __attribute__((ext_vector_type(4))) float f32x4;

__device__ __forceinline__ unsigned short f32_to_bf16(float f) {
  union { float f; unsigned int u; } v; v.f = f;
  unsigned int u = v.u;
  u += 0x7FFFu + ((u >> 16) & 1u);   // round-to-nearest-even
  return (unsigned short)(u >> 16);
}

__device__ __forceinline__ void async_copy16(const unsigned short* g, unsigned short* l) {
  __builtin_amdgcn_global_load_lds(
      (const __attribute__((address_space(1))) unsigned int*)g,
      (__attribute__((address_space(3))) unsigned int*)l,
      16, 0, 0);
}

// Kernel 1: row-normalize fp32 -> bf16 (RNE), PRE-SWIZZLED output layout.
// Within each row, global 16B k-chunk g is stored at position g ^ ((row>>1)&3)
// (permutation inside aligned 64B windows): sim kernel reads lane-linear
// (coalesced; R2 showed permuted global reads cost +44us) and LDS lands
// bank-conflict-free (R1/R3: conflicts 4.26M -> 0).
__global__ __launch_bounds__(128) void prep_kernel(
    const float* __restrict__ src, unsigned short* __restrict__ dst,
    float* __restrict__ acc) {
  const int row = blockIdx.x;
  const int tid = threadIdx.x;
  const float4 v = ((const float4*)src)[row * 128 + tid];
  float ss = v.x * v.x + v.y * v.y + v.z * v.z + v.w * v.w;
  #pragma unroll
  for (int off = 32; off > 0; off >>= 1) ss += __shfl_down(ss, off);
  __shared__ float red[2];
  __shared__ float s_rn;
  const int lane = tid & 63, w = tid >> 6;
  if (lane == 0) red[w] = ss;
  __syncthreads();
  if (tid == 0) {
    s_rn = 1.0f / sqrtf(red[0] + red[1]);   // norms ~22.6, EPS can never fire
    if (row == 0) *acc = 0.0f;
  }
  __syncthreads();
  const float rn = s_rn;
  ushort4 o;
  o.x = f32_to_bf16(v.x * rn);
  o.y = f32_to_bf16(v.y * rn);
  o.z = f32_to_bf16(v.z * rn);
  o.w = f32_to_bf16(v.w * rn);
  const int cg   = tid >> 1;                       // 16B chunk index 0..63
  const int xorv = (row >> 1) & 3;
  const int p    = (cg & 0x3C) | ((cg & 3) ^ xorv);
  ((ushort4*)dst)[row * 128 + p * 2 + (tid & 1)] = o;
}

// Kernel 2: tiled bf16 MFMA GEMM (idn @ idn^T) fused with clamp, diagonal
// masking, and full reduction. 2D grid (XCD = bj%8 -> B-set L2-resident;
// R1 A/B: 31 MB vs 74 MB fetch). Upper-tri blocks only, strictly-upper 2x.
//
// R4: 2-stage LDS double-buffer. Tile t+1's 4 global_load_lds stay in
// flight across tile t's compute: raw s_barrier + s_waitcnt vmcnt(4)
// (NOT __syncthreads, which drains vmcnt(0) and serializes the fill
// latency -- R0..R3 all paid ~300+ cyc/iter of exposed L2/HBM latency).
// Write-after-read safety: tile t+1 goes into stage (t+1)&1, which was
// last read at tile t-1 -- protected by the post-compute barrier of t-1.
__global__ __launch_bounds__(256) void sim_reduce_kernel(
    const unsigned short* __restrict__ idn, float* __restrict__ acc) {
  const int bi = blockIdx.y;
  const int bj = blockIdx.x;
  if (bj < bi) return;               // block-uniform early exit (dead block)

  __shared__ __align__(16) unsigned short As[2][BM * BK];
  __shared__ __align__(16) unsigned short Bs[2][BM * BK];
  // epilogue scratch aliases As (dead after final barrier); keeps LDS at
  // exactly 32 KB -> 5 blocks/CU (32784 B would round down to 4).
  float* red = (float*)As;

  const int tid  = threadIdx.x;      // 0..255, 4 waves
  const int lane = tid & 63;
  const int w    = tid >> 6;
  const int wr   = (w >> 1) * 64;    // wave's 64x64 quadrant
  const int wc   = (w & 1) * 64;
  const int q    = lane >> 4;        // k-chunk this lane needs (0..3)
  const int r16  = lane & 15;
  const int koff = (q ^ ((r16 >> 1) & 3)) * 8;   // deswizzle on LDS read

  f32x4 acc_f[4][4];
  #pragma unroll
  for (int i = 0; i < 4; i++)
    #pragma unroll
    for (int j = 0; j < 4; j++)
      acc_f[i][j] = (f32x4){0.f, 0.f, 0.f, 0.f};

  // Staging: chunk c -> LDS bytes [c*16,+16): wave-uniform base + lane*16,
  // lane-linear global reads (memory already holds swizzled chunk order).
  const int c0 = tid, c1 = tid + 256;
  const int oc0 = c0 * 8, oc1 = c1 * 8;
  const unsigned short* gA0 = idn + (bi * BM + (c0 >> 2)) * KDIM + (c0 & 3) * 8;
  const unsigned short* gA1 = idn + (bi * BM + (c1 >> 2)) * KDIM + (c1 & 3) * 8;
  const unsigned short* gB0 = idn + (bj * BM + (c0 >> 2)) * KDIM + (c0 & 3) * 8;
  const unsigned short* gB1 = idn + (bj * BM + (c1 >> 2)) * KDIM + (c1 & 3) * 8;

  // prologue: stage tile 0 into buffer 0
  async_copy16(gA0, &As[0][oc0]);
  async_copy16(gA1, &As[0][oc1]);
  async_copy16(gB0, &Bs[0][oc0]);
  async_copy16(gB1, &Bs[0][oc1]);

  #pragma unroll 2
  for (int t = 0; t < NKT; ++t) {
    const int cs = t & 1;
    if (t + 1 < NKT) {
      const int ns = cs ^ 1;
      const int ko = (t + 1) * BK;
      async_copy16(gA0 + ko, &As[ns][oc0]);
      async_copy16(gA1 + ko, &As[ns][oc1]);
      async_copy16(gB0 + ko, &Bs[ns][oc0]);
      async_copy16(gB1 + ko, &Bs[ns][oc1]);
      asm volatile("s_waitcnt vmcnt(4)" ::: "memory");  // tile t done; t+1 in flight
    } else {
      asm volatile("s_waitcnt vmcnt(0)" ::: "memory");  // last tile
    }
    asm volatile("s_barrier" ::: "memory");             // tile t visible to all

    bf16x8 a[4], b[4];
    #pragma unroll
    for (int mi = 0; mi < 4; mi++)   // A frag: row = lane&15, k = (lane>>4)*8+j
      a[mi] = *(const bf16x8*)&As[cs][(wr + mi * 16 + r16) * BK + koff];
    #pragma unroll
    for (int ni = 0; ni < 4; ni++)
      b[ni] = *(const bf16x8*)&Bs[cs][(wc + ni * 16 + r16) * BK + koff];
    #pragma unroll
    for (int mi = 0; mi < 4; mi++)
      #pragma unroll
      for (int ni = 0; ni < 4; ni++)
        acc_f[mi][ni] = __builtin_amdgcn_mfma_f32_16x16x32_bf16(
            a[mi], b[ni], acc_f[mi][ni], 0, 0, 0);

    asm volatile("s_barrier" ::: "memory");  // protect stage cs before reuse
  }

  // Epilogue: clamp at zero, mask diagonal, reduce.
  // C/D layout (verified m89/m91): col = lane&15, row = (lane>>4)*4 + reg.
  float local = 0.f;
  const bool diag = (bi == bj);
  #pragma unroll
  for (int mi = 0; mi < 4; mi++)
    #pragma unroll
    for (int ni = 0; ni < 4; ni++)
      #pragma unroll
      for (int rr = 0; rr < 4; rr++) {
        const int ri = wr + mi * 16 + q * 4 + rr;
        const int ci = wc + ni * 16 + r16;
        float v = fmaxf(acc_f[mi][ni][rr], 0.f);
        if (diag && ri == ci) v = 0.f;
        local += v;
      }

  #pragma unroll
  for (int off = 32; off > 0; off >>= 1) local += __shfl_down(local, off);
  if (lane == 0) red[w] = local;
  __syncthreads();
  if (tid == 0) {
    float s = red[0] + red[1] + red[2] + red[3];
    if (!diag) s *= 2.f;             // strictly-upper tiles cover both triangles
    atomicAdd(acc, s);
  }
}

// Kernel 3: scale and write both outputs (total_loss == l_id_div, DIV_COEF=1).
__global__ void finalize_kernel(const float* __restrict__ acc, float* __restrict__ out) {
  const float m = *acc * (1.0f / ((float)NROWS * (float)NROWS));
  out[0] = m;
  out[1] = m;
}

extern "C" void kernel_launch(void* const* d_in, const int* in_sizes, int n_in,
                              void* d_out, int out_size, void* d_ws, size_t ws_size,
                              hipStream_t stream) {
  const float* id = (const float*)d_in[0];
  float* out = (float*)d_out;
  unsigned short* idn = (unsigned short*)d_ws;                     // 8 MB bf16
  float* acc = (float*)((char*)d_ws + (size_t)NROWS * KDIM * 2);

  prep_kernel<<<NROWS, 128, 0, stream>>>(id, idn, acc);
  dim3 grid(NT, NT);
  sim_reduce_kernel<<<grid, 256, 0, stream>>>(idn, acc);
  finalize_kernel<<<1, 1, 0, stream>>>(acc, out);
}